// Round 1
// baseline (23407.515 us; speedup 1.0000x reference)
//
#include <hip/hip_runtime.h>
#include <hip/hip_bf16.h>

#define NFEAT 512
#define NCOL 65536   // r*c*B = 32*32*64
#define JAC_SWEEPS 10

// ---------------- K0: gather x -> im[512][65536] + row-sum partials ----------------
__global__ __launch_bounds__(256) void k_gather(const float* __restrict__ x,
                                                float* __restrict__ im,
                                                float* __restrict__ mnsum) {
  __shared__ float tile[64][129];
  int bid = blockIdx.x;
  int br = bid & 3, i = (bid >> 2) & 31, ch = bid >> 7;
  int h = i * 4 + br;
  int t = threadIdx.x;
  for (int tt = 0; tt < 32; ++tt) {
    int idx = t + 256 * tt;
    int b = idx >> 7, w = idx & 127;
    tile[b][w] = x[((size_t)(b * 32 + ch) * 128 + h) * 128 + w];
  }
  __syncthreads();
  int lane = t & 63;
  for (int bc = 0; bc < 4; ++bc) {
    int f = ch * 16 + br * 4 + bc;
    size_t base = (size_t)f * NCOL + (size_t)i * 2048;
    float local = 0.f;
    for (int tt = 0; tt < 8; ++tt) {
      int idx = t + 256 * tt;          // 0..2047  (j*64+b)
      int j = idx >> 6, b = idx & 63;
      float v = tile[b][4 * j + bc];
      im[base + idx] = v;
      local += v;
    }
    for (int off = 32; off > 0; off >>= 1) local += __shfl_xor(local, off, 64);
    if (lane == 0) atomicAdd(&mnsum[f], local);
  }
}

// ---------------- K1: mn = mnsum / NCOL ----------------
__global__ void k_mean(const float* __restrict__ mnsum, float* __restrict__ mn) {
  int i = blockIdx.x * blockDim.x + threadIdx.x;
  if (i < NFEAT) mn[i] = mnsum[i] * (1.0f / NCOL);
}

// ---------------- K2: covpart[chunk][512][512] = im[:,chunk] @ im[:,chunk]^T ----------------
__global__ __launch_bounds__(256) void k_covpart(const float* __restrict__ im,
                                                 float* __restrict__ part) {
  __shared__ float As[32][132];
  __shared__ float Bs[32][132];
  int bid = blockIdx.x;
  int tile = bid & 15, chunk = bid >> 4;
  int ti = tile >> 2, tj = tile & 3;
  int I = ti * 128, J = tj * 128;
  size_t kb = (size_t)chunk * 4096;
  int t = threadIdx.x;
  int tx = t & 15, ty = t >> 4;
  float acc[8][8] = {};
  for (int k0 = 0; k0 < 4096; k0 += 32) {
    for (int r = 0; r < 4; ++r) {
      int idx = t + 256 * r;            // 0..1023 : 128 rows x 8 float4
      int i2 = idx >> 3, c4 = idx & 7;
      float4 va = *(const float4*)&im[(size_t)(I + i2) * NCOL + kb + k0 + c4 * 4];
      As[c4 * 4 + 0][i2] = va.x; As[c4 * 4 + 1][i2] = va.y;
      As[c4 * 4 + 2][i2] = va.z; As[c4 * 4 + 3][i2] = va.w;
      float4 vb = *(const float4*)&im[(size_t)(J + i2) * NCOL + kb + k0 + c4 * 4];
      Bs[c4 * 4 + 0][i2] = vb.x; Bs[c4 * 4 + 1][i2] = vb.y;
      Bs[c4 * 4 + 2][i2] = vb.z; Bs[c4 * 4 + 3][i2] = vb.w;
    }
    __syncthreads();
    for (int kk = 0; kk < 32; ++kk) {
      float a[8], b8[8];
      *(float4*)&a[0]  = *(float4*)&As[kk][ty * 8];
      *(float4*)&a[4]  = *(float4*)&As[kk][ty * 8 + 4];
      *(float4*)&b8[0] = *(float4*)&Bs[kk][tx * 8];
      *(float4*)&b8[4] = *(float4*)&Bs[kk][tx * 8 + 4];
#pragma unroll
      for (int ai = 0; ai < 8; ++ai)
#pragma unroll
        for (int bj = 0; bj < 8; ++bj)
          acc[ai][bj] += a[ai] * b8[bj];
    }
    __syncthreads();
  }
  float* dst = &part[(size_t)chunk * NFEAT * NFEAT];
  for (int ai = 0; ai < 8; ++ai)
    for (int bj = 0; bj < 8; ++bj)
      dst[(size_t)(I + ty * 8 + ai) * NFEAT + (J + tx * 8 + bj)] = acc[ai][bj];
}

// ---------------- K3: cov finalize -> Aj stored column-major [col][row] ----------------
__global__ __launch_bounds__(256) void k_covfin(const float* __restrict__ part,
                                                const float* __restrict__ mn,
                                                float* __restrict__ Aj) {
  int i = blockIdx.x;
  for (int j = threadIdx.x; j < NFEAT; j += 256) {
    float s = 0.f;
    for (int c = 0; c < 16; ++c)
      s += part[(size_t)c * NFEAT * NFEAT + (size_t)i * NFEAT + j];
    float v = s * (1.0f / NCOL) - mn[i] * mn[j];
    Aj[(size_t)j * NFEAT + i] = v;     // column j contiguous
  }
}

// ---------------- K4: one round of block one-sided Jacobi ----------------
// 32 blocks x 16 cols; 16 WGs; each WG: 32-column union in LDS, full inner tournament.
__global__ __launch_bounds__(512) void k_jacobi(float* __restrict__ Aj, int rr) {
  __shared__ float cols[32][512];      // 64 KiB
  int g = blockIdx.x;                  // 0..15
  int t = threadIdx.x;
  int P, Q;
  if (g == 0) { P = 31; Q = rr; }
  else { P = (rr + g) % 31; Q = (rr + 31 - g) % 31; }
  for (int idx = t; idx < 32 * 512; idx += 512) {
    int c = idx >> 9, r = idx & 511;
    int gc = (c < 16) ? (P * 16 + c) : (Q * 16 + (c - 16));
    cols[c][r] = Aj[(size_t)gc * NFEAT + r];
  }
  __syncthreads();
  int w = t >> 6, l = t & 63;
  for (int ir = 0; ir < 31; ++ir) {
#pragma unroll
    for (int kk = 0; kk < 2; ++kk) {
      int k = w + kk * 8;
      int p, q;
      if (k == 0) { p = 31; q = ir; }
      else { p = (ir + k) % 31; q = (ir + 31 - k) % 31; }
      float pv[8], qv[8];
      float app = 0.f, aqq = 0.f, apq = 0.f;
#pragma unroll
      for (int e = 0; e < 8; ++e) {
        pv[e] = cols[p][l + 64 * e];
        qv[e] = cols[q][l + 64 * e];
        app += pv[e] * pv[e];
        aqq += qv[e] * qv[e];
        apq += pv[e] * qv[e];
      }
      for (int off = 32; off > 0; off >>= 1) {
        app += __shfl_xor(app, off, 64);
        aqq += __shfl_xor(aqq, off, 64);
        apq += __shfl_xor(apq, off, 64);
      }
      if (apq * apq > 1e-24f * app * aqq) {
        float tau = (aqq - app) / (2.f * apq);
        float th  = copysignf(1.f / (fabsf(tau) + sqrtf(1.f + tau * tau)), tau);
        float cf  = 1.0f / sqrtf(1.f + th * th);
        float sf  = cf * th;
#pragma unroll
        for (int e = 0; e < 8; ++e) {
          float np = cf * pv[e] - sf * qv[e];
          float nq = sf * pv[e] + cf * qv[e];
          cols[p][l + 64 * e] = np;
          cols[q][l + 64 * e] = nq;
        }
      }
    }
    __syncthreads();
  }
  for (int idx = t; idx < 32 * 512; idx += 512) {
    int c = idx >> 9, r = idx & 511;
    int gc = (c < 16) ? (P * 16 + c) : (Q * 16 + (c - 16));
    Aj[(size_t)gc * NFEAT + r] = cols[c][r];
  }
}

// ---------------- K5: finalize eig: norms -> s; normalize cols -> U, Ut; stdd; utmn ----------------
__global__ __launch_bounds__(256) void k_eigfin(const float* __restrict__ Aj,
                                                const float* __restrict__ mn,
                                                float* __restrict__ U,
                                                float* __restrict__ Ut,
                                                float* __restrict__ stddv,
                                                float* __restrict__ istdd,
                                                float* __restrict__ utmn) {
  __shared__ float red[4];
  int j = blockIdx.x, t = threadIdx.x;
  const float* col = &Aj[(size_t)j * NFEAT];
  float v0 = col[t], v1 = col[t + 256];
  float ss = v0 * v0 + v1 * v1;
  for (int off = 32; off > 0; off >>= 1) ss += __shfl_xor(ss, off, 64);
  if ((t & 63) == 0) red[t >> 6] = ss;
  __syncthreads();
  float lam = sqrtf(red[0] + red[1] + red[2] + red[3]);   // eigenvalue
  float inv = 1.0f / lam;
  float u0 = v0 * inv, u1 = v1 * inv;
  Ut[(size_t)j * NFEAT + t] = u0;
  Ut[(size_t)j * NFEAT + t + 256] = u1;
  U[(size_t)t * NFEAT + j] = u0;
  U[(size_t)(t + 256) * NFEAT + j] = u1;
  float dm = u0 * mn[t] + u1 * mn[t + 256];
  for (int off = 32; off > 0; off >>= 1) dm += __shfl_xor(dm, off, 64);
  __syncthreads();
  if ((t & 63) == 0) red[t >> 6] = dm;
  __syncthreads();
  if (t == 0) {
    utmn[j]  = red[0] + red[1] + red[2] + red[3];
    stddv[j] = sqrtf(lam);
    istdd[j] = 1.0f / sqrtf(lam);
  }
}

// ---------------- K6: proj + quantize:  Y = quant((Ut@im - utmn)/stdd) * stdd ----------------
__global__ __launch_bounds__(256) void k_proj(const float* __restrict__ im,
                                              const float* __restrict__ Ut,
                                              const float* __restrict__ utmn,
                                              const float* __restrict__ stddv,
                                              const float* __restrict__ istdd,
                                              const float* __restrict__ clampv,
                                              const int* __restrict__ bitsp,
                                              float* __restrict__ Y) {
  __shared__ float As[32][132];
  __shared__ float Bs[32][132];
  int bx = blockIdx.x;
  int ft = bx & 3;
  int nt = bx >> 2;
  int F0 = ft * 128;
  size_t N0 = (size_t)nt * 128;
  int t = threadIdx.x;
  int tx = t & 15, ty = t >> 4;
  float acc[8][8] = {};
  for (int k0 = 0; k0 < 512; k0 += 32) {
    for (int r = 0; r < 4; ++r) {
      int idx = t + 256 * r;
      int fi = idx >> 3, c4 = idx & 7;
      float4 v = *(const float4*)&Ut[(size_t)(F0 + fi) * NFEAT + k0 + c4 * 4];
      As[c4 * 4 + 0][fi] = v.x; As[c4 * 4 + 1][fi] = v.y;
      As[c4 * 4 + 2][fi] = v.z; As[c4 * 4 + 3][fi] = v.w;
    }
    for (int r = 0; r < 4; ++r) {
      int idx = t + 256 * r;            // 32 rows x 32 float4
      int kk = idx >> 5, c4 = idx & 31;
      float4 v = *(const float4*)&im[(size_t)(k0 + kk) * NCOL + N0 + c4 * 4];
      *(float4*)&Bs[kk][c4 * 4] = v;
    }
    __syncthreads();
    for (int kk = 0; kk < 32; ++kk) {
      float a[8], b8[8];
      *(float4*)&a[0]  = *(float4*)&As[kk][ty * 8];
      *(float4*)&a[4]  = *(float4*)&As[kk][ty * 8 + 4];
      *(float4*)&b8[0] = *(float4*)&Bs[kk][tx * 8];
      *(float4*)&b8[4] = *(float4*)&Bs[kk][tx * 8 + 4];
#pragma unroll
      for (int ai = 0; ai < 8; ++ai)
#pragma unroll
        for (int bj = 0; bj < 8; ++bj)
          acc[ai][bj] += a[ai] * b8[bj];
    }
    __syncthreads();
  }
  float cv = clampv[0];
  float levels = (float)((1 << bitsp[0]) - 1);
  float scale = levels / (2.0f * cv);
  for (int ai = 0; ai < 8; ++ai) {
    int f = F0 + ty * 8 + ai;
    float um = utmn[f], is = istdd[f], sd = stddv[f];
    float tmp[8];
#pragma unroll
    for (int bj = 0; bj < 8; ++bj) {
      float v = (acc[ai][bj] - um) * is;
      v = fminf(fmaxf(v, -cv), cv);
      float r = (v + cv) * scale;
      float rq = rintf(r);
      tmp[bj] = (rq / scale - cv) * sd;
    }
    float* dst = &Y[(size_t)f * NCOL + N0 + tx * 8];
    *(float4*)&dst[0] = *(float4*)&tmp[0];
    *(float4*)&dst[4] = *(float4*)&tmp[4];
  }
}

// ---------------- K7: reconstruct: rec = U @ Y + mn ----------------
__global__ __launch_bounds__(256) void k_rec(const float* __restrict__ Y,
                                             const float* __restrict__ U,
                                             const float* __restrict__ mn,
                                             float* __restrict__ rec) {
  __shared__ float As[32][132];
  __shared__ float Bs[32][132];
  int bx = blockIdx.x;
  int kt = bx & 3;
  int nt = bx >> 2;
  int K0 = kt * 128;
  size_t N0 = (size_t)nt * 128;
  int t = threadIdx.x;
  int tx = t & 15, ty = t >> 4;
  float acc[8][8] = {};
  for (int f0 = 0; f0 < 512; f0 += 32) {
    for (int r = 0; r < 4; ++r) {
      int idx = t + 256 * r;
      int ki = idx >> 3, c4 = idx & 7;
      float4 v = *(const float4*)&U[(size_t)(K0 + ki) * NFEAT + f0 + c4 * 4];
      As[c4 * 4 + 0][ki] = v.x; As[c4 * 4 + 1][ki] = v.y;
      As[c4 * 4 + 2][ki] = v.z; As[c4 * 4 + 3][ki] = v.w;
    }
    for (int r = 0; r < 4; ++r) {
      int idx = t + 256 * r;
      int ff = idx >> 5, c4 = idx & 31;
      float4 v = *(const float4*)&Y[(size_t)(f0 + ff) * NCOL + N0 + c4 * 4];
      *(float4*)&Bs[ff][c4 * 4] = v;
    }
    __syncthreads();
    for (int ff = 0; ff < 32; ++ff) {
      float a[8], b8[8];
      *(float4*)&a[0]  = *(float4*)&As[ff][ty * 8];
      *(float4*)&a[4]  = *(float4*)&As[ff][ty * 8 + 4];
      *(float4*)&b8[0] = *(float4*)&Bs[ff][tx * 8];
      *(float4*)&b8[4] = *(float4*)&Bs[ff][tx * 8 + 4];
#pragma unroll
      for (int ai = 0; ai < 8; ++ai)
#pragma unroll
        for (int bj = 0; bj < 8; ++bj)
          acc[ai][bj] += a[ai] * b8[bj];
    }
    __syncthreads();
  }
  for (int ai = 0; ai < 8; ++ai) {
    int kr = K0 + ty * 8 + ai;
    float m = mn[kr];
    float tmp[8];
#pragma unroll
    for (int bj = 0; bj < 8; ++bj) tmp[bj] = acc[ai][bj] + m;
    float* dst = &rec[(size_t)kr * NCOL + N0 + tx * 8];
    *(float4*)&dst[0] = *(float4*)&tmp[0];
    *(float4*)&dst[4] = *(float4*)&tmp[4];
  }
}

// ---------------- K8: scatter rec[512][65536] -> out (B,C,H,W) ----------------
__global__ __launch_bounds__(256) void k_scatter(const float* __restrict__ rec,
                                                 float* __restrict__ out) {
  __shared__ float tile[64][129];
  int bid = blockIdx.x;
  int br = bid & 3, i = (bid >> 2) & 31, ch = bid >> 7;
  int h = i * 4 + br;
  int t = threadIdx.x;
  for (int bc = 0; bc < 4; ++bc) {
    int f = ch * 16 + br * 4 + bc;
    size_t base = (size_t)f * NCOL + (size_t)i * 2048;
    for (int tt = 0; tt < 8; ++tt) {
      int idx = t + 256 * tt;
      int j = idx >> 6, b = idx & 63;
      tile[b][4 * j + bc] = rec[base + idx];
    }
  }
  __syncthreads();
  for (int tt = 0; tt < 32; ++tt) {
    int idx = t + 256 * tt;
    int b = idx >> 7, w = idx & 127;
    out[((size_t)(b * 32 + ch) * 128 + h) * 128 + w] = tile[b][w];
  }
}

extern "C" void kernel_launch(void* const* d_in, const int* in_sizes, int n_in,
                              void* d_out, int out_size, void* d_ws, size_t ws_size,
                              hipStream_t stream) {
  const float* x      = (const float*)d_in[0];
  const float* clampv = (const float*)d_in[1];
  const int*   bitsp  = (const int*)d_in[3];

  float* ws    = (float*)d_ws;
  float* im    = ws;                                   // 512*65536
  float* Y     = im + (size_t)NFEAT * NCOL;            // 512*65536
  float* part  = Y + (size_t)NFEAT * NCOL;             // 16*512*512
  float* Aj    = part + (size_t)16 * NFEAT * NFEAT;    // 512*512
  float* U     = Aj + (size_t)NFEAT * NFEAT;           // 512*512 [k][f]
  float* Ut    = U + (size_t)NFEAT * NFEAT;            // 512*512 [f][k]
  float* mnsum = Ut + (size_t)NFEAT * NFEAT;           // 512
  float* mn    = mnsum + NFEAT;
  float* stddv = mn + NFEAT;
  float* istdd = stddv + NFEAT;
  float* utmn  = istdd + NFEAT;
  float* rbuf  = im;                                   // reuse im for rec

  hipMemsetAsync(mnsum, 0, NFEAT * sizeof(float), stream);
  k_gather<<<4096, 256, 0, stream>>>(x, im, mnsum);
  k_mean<<<2, 256, 0, stream>>>(mnsum, mn);
  k_covpart<<<256, 256, 0, stream>>>(im, part);
  k_covfin<<<512, 256, 0, stream>>>(part, mn, Aj);
  for (int s = 0; s < JAC_SWEEPS; ++s)
    for (int rr = 0; rr < 31; ++rr)
      k_jacobi<<<16, 512, 0, stream>>>(Aj, rr);
  k_eigfin<<<512, 256, 0, stream>>>(Aj, mn, U, Ut, stddv, istdd, utmn);
  k_proj<<<2048, 256, 0, stream>>>(im, Ut, utmn, stddv, istdd, clampv, bitsp, Y);
  k_rec<<<2048, 256, 0, stream>>>(Y, U, mn, rbuf);
  k_scatter<<<4096, 256, 0, stream>>>(rbuf, (float*)d_out);
}

// Round 2
// 14242.719 us; speedup vs baseline: 1.6435x; 1.6435x over previous
//
#include <hip/hip_runtime.h>
#include <hip/hip_bf16.h>

#define NFEAT 512
#define NCOL 65536   // r*c*B = 32*32*64
#define JAC_SWEEPS 10

typedef short bf16x8 __attribute__((ext_vector_type(8)));
typedef float f32x4 __attribute__((ext_vector_type(4)));

// ---------------- K0: gather x -> im[512][65536] + row-sum partials ----------------
__global__ __launch_bounds__(256) void k_gather(const float* __restrict__ x,
                                                float* __restrict__ im,
                                                float* __restrict__ mnsum) {
  __shared__ float tile[64][129];
  int bid = blockIdx.x;
  int br = bid & 3, i = (bid >> 2) & 31, ch = bid >> 7;
  int h = i * 4 + br;
  int t = threadIdx.x;
  for (int tt = 0; tt < 32; ++tt) {
    int idx = t + 256 * tt;
    int b = idx >> 7, w = idx & 127;
    tile[b][w] = x[((size_t)(b * 32 + ch) * 128 + h) * 128 + w];
  }
  __syncthreads();
  int lane = t & 63;
  for (int bc = 0; bc < 4; ++bc) {
    int f = ch * 16 + br * 4 + bc;
    size_t base = (size_t)f * NCOL + (size_t)i * 2048;
    float local = 0.f;
    for (int tt = 0; tt < 8; ++tt) {
      int idx = t + 256 * tt;          // 0..2047  (j*64+b)
      int j = idx >> 6, b = idx & 63;
      float v = tile[b][4 * j + bc];
      im[base + idx] = v;
      local += v;
    }
    for (int off = 32; off > 0; off >>= 1) local += __shfl_xor(local, off, 64);
    if (lane == 0) atomicAdd(&mnsum[f], local);
  }
}

// ---------------- K1: mn = mnsum / NCOL ----------------
__global__ void k_mean(const float* __restrict__ mnsum, float* __restrict__ mn) {
  int i = blockIdx.x * blockDim.x + threadIdx.x;
  if (i < NFEAT) mn[i] = mnsum[i] * (1.0f / NCOL);
}

// ---------------- K2: covpart[chunk][512][512] = im[:,chunk] @ im[:,chunk]^T ----------------
__global__ __launch_bounds__(256) void k_covpart(const float* __restrict__ im,
                                                 float* __restrict__ part) {
  __shared__ float As[32][132];
  __shared__ float Bs[32][132];
  int bid = blockIdx.x;
  int tile = bid & 15, chunk = bid >> 4;
  int ti = tile >> 2, tj = tile & 3;
  int I = ti * 128, J = tj * 128;
  size_t kb = (size_t)chunk * 4096;
  int t = threadIdx.x;
  int tx = t & 15, ty = t >> 4;
  float acc[8][8] = {};
  for (int k0 = 0; k0 < 4096; k0 += 32) {
    for (int r = 0; r < 4; ++r) {
      int idx = t + 256 * r;            // 0..1023 : 128 rows x 8 float4
      int i2 = idx >> 3, c4 = idx & 7;
      float4 va = *(const float4*)&im[(size_t)(I + i2) * NCOL + kb + k0 + c4 * 4];
      As[c4 * 4 + 0][i2] = va.x; As[c4 * 4 + 1][i2] = va.y;
      As[c4 * 4 + 2][i2] = va.z; As[c4 * 4 + 3][i2] = va.w;
      float4 vb = *(const float4*)&im[(size_t)(J + i2) * NCOL + kb + k0 + c4 * 4];
      Bs[c4 * 4 + 0][i2] = vb.x; Bs[c4 * 4 + 1][i2] = vb.y;
      Bs[c4 * 4 + 2][i2] = vb.z; Bs[c4 * 4 + 3][i2] = vb.w;
    }
    __syncthreads();
    for (int kk = 0; kk < 32; ++kk) {
      float a[8], b8[8];
      *(float4*)&a[0]  = *(float4*)&As[kk][ty * 8];
      *(float4*)&a[4]  = *(float4*)&As[kk][ty * 8 + 4];
      *(float4*)&b8[0] = *(float4*)&Bs[kk][tx * 8];
      *(float4*)&b8[4] = *(float4*)&Bs[kk][tx * 8 + 4];
#pragma unroll
      for (int ai = 0; ai < 8; ++ai)
#pragma unroll
        for (int bj = 0; bj < 8; ++bj)
          acc[ai][bj] += a[ai] * b8[bj];
    }
    __syncthreads();
  }
  float* dst = &part[(size_t)chunk * NFEAT * NFEAT];
  for (int ai = 0; ai < 8; ++ai)
    for (int bj = 0; bj < 8; ++bj)
      dst[(size_t)(I + ty * 8 + ai) * NFEAT + (J + tx * 8 + bj)] = acc[ai][bj];
}

// ---------------- K3: cov finalize -> Aj stored column-major [col][row] ----------------
__global__ __launch_bounds__(256) void k_covfin(const float* __restrict__ part,
                                                const float* __restrict__ mn,
                                                float* __restrict__ Aj) {
  int i = blockIdx.x;
  for (int j = threadIdx.x; j < NFEAT; j += 256) {
    float s = 0.f;
    for (int c = 0; c < 16; ++c)
      s += part[(size_t)c * NFEAT * NFEAT + (size_t)i * NFEAT + j];
    float v = s * (1.0f / NCOL) - mn[i] * mn[j];
    Aj[(size_t)j * NFEAT + i] = v;     // column j contiguous
  }
}

// ---------------- K4: persistent block one-sided Jacobi (Gram + rotation-accumulate) ----
// 16 WGs x 512 thr. Per outer round per WG: load 32 cols -> LDS; G=V^T V via
// bf16-split MFMA; wave0 runs 31-round inner tournament on G accumulating Rt;
// all threads apply V<-V*R writing to global; monotonic atomic grid barrier.
__global__ __launch_bounds__(512) void k_jacobi_persist(float* __restrict__ Aj,
                                                        unsigned int* __restrict__ bar) {
  __shared__ float Vf[32][524];        // 32 cols x 512 rows (col-major), pad 524
  __shared__ float G[32][36];
  __shared__ float Tt[32][36];
  __shared__ float Rt[32][36];         // Rt[j][k] = R[k][j]
  __shared__ float Gp[8][256];
  __shared__ float cs[32];

  const int g = blockIdx.x;
  const int t = threadIdx.x;
  const int w = t >> 6, l = t & 63;
  unsigned int tgt = 0;

  for (int sweep = 0; sweep < JAC_SWEEPS; ++sweep)
  for (int rr = 0; rr < 31; ++rr) {
    int P, Q;
    if (g == 0) { P = 31; Q = rr; }
    else { P = (rr + g) % 31; Q = (rr + 31 - g) % 31; }

    // ---- load 32 columns (f32) into LDS + init Rt = I ----
    {
      int c = t >> 4;
      int r0 = (t & 15) * 32;
      int gc = (c < 16) ? P * 16 + c : Q * 16 + (c - 16);
      const float4* src = (const float4*)&Aj[(size_t)gc * NFEAT + r0];
#pragma unroll
      for (int i = 0; i < 8; ++i)
        *(float4*)&Vf[c][r0 + 4 * i] = src[i];
      int e = t;
      Rt[e >> 5][e & 31] = ((e >> 5) == (e & 31)) ? 1.f : 0.f;
      e = t + 512;
      Rt[e >> 5][e & 31] = ((e >> 5) == (e & 31)) ? 1.f : 0.f;
    }
    __syncthreads();

    // ---- G = V^T V via bf16-split MFMA (3 terms: hh, hl, lh) ----
    {
      int tl = w & 3;                  // output tile (2x2 tiles of 16x16)
      int ti = tl >> 1, tj = tl & 1;
      int kh = w >> 2;                 // K half
      f32x4 acc = {0.f, 0.f, 0.f, 0.f};
      int a = 16 * ti + (l & 15);
      int b = 16 * tj + (l & 15);
      int rbase = 256 * kh + 8 * (l >> 4);
      for (int kk = 0; kk < 8; ++kk) {
        int r = rbase + 32 * kk;
        float av[8], bv[8];
        *(float4*)&av[0] = *(const float4*)&Vf[a][r];
        *(float4*)&av[4] = *(const float4*)&Vf[a][r + 4];
        *(float4*)&bv[0] = *(const float4*)&Vf[b][r];
        *(float4*)&bv[4] = *(const float4*)&Vf[b][r + 4];
        bf16x8 ah, al2, bh, bl2;
#pragma unroll
        for (int j = 0; j < 8; ++j) {
          unsigned int au = __float_as_uint(av[j]);
          ah[j] = (short)(au >> 16);
          float ares = av[j] - __uint_as_float(au & 0xffff0000u);
          al2[j] = (short)(__float_as_uint(ares) >> 16);
          unsigned int bu = __float_as_uint(bv[j]);
          bh[j] = (short)(bu >> 16);
          float bres = bv[j] - __uint_as_float(bu & 0xffff0000u);
          bl2[j] = (short)(__float_as_uint(bres) >> 16);
        }
        acc = __builtin_amdgcn_mfma_f32_16x16x32_bf16(ah, bh, acc, 0, 0, 0);
        acc = __builtin_amdgcn_mfma_f32_16x16x32_bf16(ah, bl2, acc, 0, 0, 0);
        acc = __builtin_amdgcn_mfma_f32_16x16x32_bf16(al2, bh, acc, 0, 0, 0);
      }
      *(f32x4*)&Gp[w][l * 4] = acc;
    }
    __syncthreads();
    {
#pragma unroll
      for (int e2 = 0; e2 < 2; ++e2) {
        int e = t + 512 * e2;
        int tl = e >> 8, idx = e & 255;
        float v = Gp[tl][idx] + Gp[tl + 4][idx];
        int ll = idx >> 2, q = idx & 3;
        int row = 16 * (tl >> 1) + (ll >> 4) * 4 + q;
        int col = 16 * (tl & 1) + (ll & 15);
        G[row][col] = v;
      }
    }
    __syncthreads();

    // ---- tournament on G (wave 0 only, in-wave lockstep) ----
    if (w == 0) {
      for (int ir = 0; ir < 31; ++ir) {
        // phase 0: lanes 0..15 compute rotations
        if (l < 16) {
          int k = l, p, q;
          if (k == 0) { p = 31; q = ir; }
          else { p = (ir + k) % 31; q = (ir + 31 - k) % 31; }
          float app = G[p][p], aqq = G[q][q], apq = G[p][q];
          float cc = 1.f, ssv = 0.f;
          if (apq * apq > 1e-24f * app * aqq) {
            float tau = (aqq - app) / (2.f * apq);
            float th  = copysignf(1.f / (fabsf(tau) + sqrtf(1.f + tau * tau)), tau);
            cc = 1.0f / sqrtf(1.f + th * th);
            ssv = cc * th;
          }
          cs[2 * k] = cc; cs[2 * k + 1] = ssv;
        }
        __builtin_amdgcn_sched_barrier(0);
        int k = l >> 2, cq = l & 3, p, q;
        if (k == 0) { p = 31; q = ir; }
        else { p = (ir + k) % 31; q = (ir + 31 - k) % 31; }
        float cc = cs[2 * k], ssv = cs[2 * k + 1];
        int c0 = 8 * cq;
        // phase A: T = J^T G, stored transposed (Tt[j][i] = T[i][j])
        float gp[8], gq[8];
        *(float4*)&gp[0] = *(const float4*)&G[p][c0];
        *(float4*)&gp[4] = *(const float4*)&G[p][c0 + 4];
        *(float4*)&gq[0] = *(const float4*)&G[q][c0];
        *(float4*)&gq[4] = *(const float4*)&G[q][c0 + 4];
#pragma unroll
        for (int i = 0; i < 8; ++i) {
          Tt[c0 + i][p] = cc * gp[i] - ssv * gq[i];
          Tt[c0 + i][q] = ssv * gp[i] + cc * gq[i];
        }
        __builtin_amdgcn_sched_barrier(0);
        // phase B: G' = T J, written symmetric (G'[p][i] = G'[i][p])
        float tp[8], tq[8];
        *(float4*)&tp[0] = *(const float4*)&Tt[p][c0];
        *(float4*)&tp[4] = *(const float4*)&Tt[p][c0 + 4];
        *(float4*)&tq[0] = *(const float4*)&Tt[q][c0];
        *(float4*)&tq[4] = *(const float4*)&Tt[q][c0 + 4];
#pragma unroll
        for (int i = 0; i < 8; ++i) {
          G[p][c0 + i] = cc * tp[i] - ssv * tq[i];
          G[q][c0 + i] = ssv * tp[i] + cc * tq[i];
        }
        // phase C: Rt rows (cols of R): same rotation form
        float rp2[8], rq2[8];
        *(float4*)&rp2[0] = *(const float4*)&Rt[p][c0];
        *(float4*)&rp2[4] = *(const float4*)&Rt[p][c0 + 4];
        *(float4*)&rq2[0] = *(const float4*)&Rt[q][c0];
        *(float4*)&rq2[4] = *(const float4*)&Rt[q][c0 + 4];
#pragma unroll
        for (int i = 0; i < 8; ++i) {
          Rt[p][c0 + i] = cc * rp2[i] - ssv * rq2[i];
          Rt[q][c0 + i] = ssv * rp2[i] + cc * rq2[i];
        }
        __builtin_amdgcn_sched_barrier(0);
      }
    }
    __syncthreads();

    // ---- apply V' = V * R, store to global ----
    {
      int r = t;
      float v[32];
#pragma unroll
      for (int k2 = 0; k2 < 32; ++k2) v[k2] = Vf[k2][r];
#pragma unroll 2
      for (int j = 0; j < 32; ++j) {
        const float4* rp = (const float4*)&Rt[j][0];
        float acc2 = 0.f;
#pragma unroll
        for (int h = 0; h < 8; ++h) {
          float4 rv = rp[h];
          acc2 += v[4 * h + 0] * rv.x;
          acc2 += v[4 * h + 1] * rv.y;
          acc2 += v[4 * h + 2] * rv.z;
          acc2 += v[4 * h + 3] * rv.w;
        }
        int gc = (j < 16) ? P * 16 + j : Q * 16 + (j - 16);
        Aj[(size_t)gc * NFEAT + r] = acc2;
      }
    }

    // ---- grid barrier (monotonic) ----
    __threadfence();
    __syncthreads();
    tgt += 16;
    if (t == 0) {
      __hip_atomic_fetch_add(bar, 1u, __ATOMIC_RELEASE, __HIP_MEMORY_SCOPE_AGENT);
      while (__hip_atomic_load(bar, __ATOMIC_ACQUIRE, __HIP_MEMORY_SCOPE_AGENT) < tgt)
        __builtin_amdgcn_s_sleep(2);
    }
    __syncthreads();
  }
}

// ---------------- K5: finalize eig: norms -> s; normalize cols -> U, Ut; stdd; utmn ----------------
__global__ __launch_bounds__(256) void k_eigfin(const float* __restrict__ Aj,
                                                const float* __restrict__ mn,
                                                float* __restrict__ U,
                                                float* __restrict__ Ut,
                                                float* __restrict__ stddv,
                                                float* __restrict__ istdd,
                                                float* __restrict__ utmn) {
  __shared__ float red[4];
  int j = blockIdx.x, t = threadIdx.x;
  const float* col = &Aj[(size_t)j * NFEAT];
  float v0 = col[t], v1 = col[t + 256];
  float ss = v0 * v0 + v1 * v1;
  for (int off = 32; off > 0; off >>= 1) ss += __shfl_xor(ss, off, 64);
  if ((t & 63) == 0) red[t >> 6] = ss;
  __syncthreads();
  float lam = sqrtf(red[0] + red[1] + red[2] + red[3]);   // eigenvalue
  float inv = 1.0f / lam;
  float u0 = v0 * inv, u1 = v1 * inv;
  Ut[(size_t)j * NFEAT + t] = u0;
  Ut[(size_t)j * NFEAT + t + 256] = u1;
  U[(size_t)t * NFEAT + j] = u0;
  U[(size_t)(t + 256) * NFEAT + j] = u1;
  float dm = u0 * mn[t] + u1 * mn[t + 256];
  for (int off = 32; off > 0; off >>= 1) dm += __shfl_xor(dm, off, 64);
  __syncthreads();
  if ((t & 63) == 0) red[t >> 6] = dm;
  __syncthreads();
  if (t == 0) {
    utmn[j]  = red[0] + red[1] + red[2] + red[3];
    stddv[j] = sqrtf(lam);
    istdd[j] = 1.0f / sqrtf(lam);
  }
}

// ---------------- K6: proj + quantize:  Y = quant((Ut@im - utmn)/stdd) * stdd ----------------
__global__ __launch_bounds__(256) void k_proj(const float* __restrict__ im,
                                              const float* __restrict__ Ut,
                                              const float* __restrict__ utmn,
                                              const float* __restrict__ stddv,
                                              const float* __restrict__ istdd,
                                              const float* __restrict__ clampv,
                                              const int* __restrict__ bitsp,
                                              float* __restrict__ Y) {
  __shared__ float As[32][132];
  __shared__ float Bs[32][132];
  int bx = blockIdx.x;
  int ft = bx & 3;
  int nt = bx >> 2;
  int F0 = ft * 128;
  size_t N0 = (size_t)nt * 128;
  int t = threadIdx.x;
  int tx = t & 15, ty = t >> 4;
  float acc[8][8] = {};
  for (int k0 = 0; k0 < 512; k0 += 32) {
    for (int r = 0; r < 4; ++r) {
      int idx = t + 256 * r;
      int fi = idx >> 3, c4 = idx & 7;
      float4 v = *(const float4*)&Ut[(size_t)(F0 + fi) * NFEAT + k0 + c4 * 4];
      As[c4 * 4 + 0][fi] = v.x; As[c4 * 4 + 1][fi] = v.y;
      As[c4 * 4 + 2][fi] = v.z; As[c4 * 4 + 3][fi] = v.w;
    }
    for (int r = 0; r < 4; ++r) {
      int idx = t + 256 * r;            // 32 rows x 32 float4
      int kk = idx >> 5, c4 = idx & 31;
      float4 v = *(const float4*)&im[(size_t)(k0 + kk) * NCOL + N0 + c4 * 4];
      *(float4*)&Bs[kk][c4 * 4] = v;
    }
    __syncthreads();
    for (int kk = 0; kk < 32; ++kk) {
      float a[8], b8[8];
      *(float4*)&a[0]  = *(float4*)&As[kk][ty * 8];
      *(float4*)&a[4]  = *(float4*)&As[kk][ty * 8 + 4];
      *(float4*)&b8[0] = *(float4*)&Bs[kk][tx * 8];
      *(float4*)&b8[4] = *(float4*)&Bs[kk][tx * 8 + 4];
#pragma unroll
      for (int ai = 0; ai < 8; ++ai)
#pragma unroll
        for (int bj = 0; bj < 8; ++bj)
          acc[ai][bj] += a[ai] * b8[bj];
    }
    __syncthreads();
  }
  float cv = clampv[0];
  float levels = (float)((1 << bitsp[0]) - 1);
  float scale = levels / (2.0f * cv);
  for (int ai = 0; ai < 8; ++ai) {
    int f = F0 + ty * 8 + ai;
    float um = utmn[f], is = istdd[f], sd = stddv[f];
    float tmp[8];
#pragma unroll
    for (int bj = 0; bj < 8; ++bj) {
      float v = (acc[ai][bj] - um) * is;
      v = fminf(fmaxf(v, -cv), cv);
      float r = (v + cv) * scale;
      float rq = rintf(r);
      tmp[bj] = (rq / scale - cv) * sd;
    }
    float* dst = &Y[(size_t)f * NCOL + N0 + tx * 8];
    *(float4*)&dst[0] = *(float4*)&tmp[0];
    *(float4*)&dst[4] = *(float4*)&tmp[4];
  }
}

// ---------------- K7: reconstruct: rec = U @ Y + mn ----------------
__global__ __launch_bounds__(256) void k_rec(const float* __restrict__ Y,
                                             const float* __restrict__ U,
                                             const float* __restrict__ mn,
                                             float* __restrict__ rec) {
  __shared__ float As[32][132];
  __shared__ float Bs[32][132];
  int bx = blockIdx.x;
  int kt = bx & 3;
  int nt = bx >> 2;
  int K0 = kt * 128;
  size_t N0 = (size_t)nt * 128;
  int t = threadIdx.x;
  int tx = t & 15, ty = t >> 4;
  float acc[8][8] = {};
  for (int f0 = 0; f0 < 512; f0 += 32) {
    for (int r = 0; r < 4; ++r) {
      int idx = t + 256 * r;
      int ki = idx >> 3, c4 = idx & 7;
      float4 v = *(const float4*)&U[(size_t)(K0 + ki) * NFEAT + f0 + c4 * 4];
      As[c4 * 4 + 0][ki] = v.x; As[c4 * 4 + 1][ki] = v.y;
      As[c4 * 4 + 2][ki] = v.z; As[c4 * 4 + 3][ki] = v.w;
    }
    for (int r = 0; r < 4; ++r) {
      int idx = t + 256 * r;
      int ff = idx >> 5, c4 = idx & 31;
      float4 v = *(const float4*)&Y[(size_t)(f0 + ff) * NCOL + N0 + c4 * 4];
      *(float4*)&Bs[ff][c4 * 4] = v;
    }
    __syncthreads();
    for (int ff = 0; ff < 32; ++ff) {
      float a[8], b8[8];
      *(float4*)&a[0]  = *(float4*)&As[ff][ty * 8];
      *(float4*)&a[4]  = *(float4*)&As[ff][ty * 8 + 4];
      *(float4*)&b8[0] = *(float4*)&Bs[ff][tx * 8];
      *(float4*)&b8[4] = *(float4*)&Bs[ff][tx * 8 + 4];
#pragma unroll
      for (int ai = 0; ai < 8; ++ai)
#pragma unroll
        for (int bj = 0; bj < 8; ++bj)
          acc[ai][bj] += a[ai] * b8[bj];
    }
    __syncthreads();
  }
  for (int ai = 0; ai < 8; ++ai) {
    int kr = K0 + ty * 8 + ai;
    float m = mn[kr];
    float tmp[8];
#pragma unroll
    for (int bj = 0; bj < 8; ++bj) tmp[bj] = acc[ai][bj] + m;
    float* dst = &rec[(size_t)kr * NCOL + N0 + tx * 8];
    *(float4*)&dst[0] = *(float4*)&tmp[0];
    *(float4*)&dst[4] = *(float4*)&tmp[4];
  }
}

// ---------------- K8: scatter rec[512][65536] -> out (B,C,H,W) ----------------
__global__ __launch_bounds__(256) void k_scatter(const float* __restrict__ rec,
                                                 float* __restrict__ out) {
  __shared__ float tile[64][129];
  int bid = blockIdx.x;
  int br = bid & 3, i = (bid >> 2) & 31, ch = bid >> 7;
  int h = i * 4 + br;
  int t = threadIdx.x;
  for (int bc = 0; bc < 4; ++bc) {
    int f = ch * 16 + br * 4 + bc;
    size_t base = (size_t)f * NCOL + (size_t)i * 2048;
    for (int tt = 0; tt < 8; ++tt) {
      int idx = t + 256 * tt;
      int j = idx >> 6, b = idx & 63;
      tile[b][4 * j + bc] = rec[base + idx];
    }
  }
  __syncthreads();
  for (int tt = 0; tt < 32; ++tt) {
    int idx = t + 256 * tt;
    int b = idx >> 7, w = idx & 127;
    out[((size_t)(b * 32 + ch) * 128 + h) * 128 + w] = tile[b][w];
  }
}

extern "C" void kernel_launch(void* const* d_in, const int* in_sizes, int n_in,
                              void* d_out, int out_size, void* d_ws, size_t ws_size,
                              hipStream_t stream) {
  const float* x      = (const float*)d_in[0];
  const float* clampv = (const float*)d_in[1];
  const int*   bitsp  = (const int*)d_in[3];

  float* ws    = (float*)d_ws;
  float* im    = ws;                                   // 512*65536
  float* Y     = im + (size_t)NFEAT * NCOL;            // 512*65536
  float* part  = Y + (size_t)NFEAT * NCOL;             // 16*512*512
  float* Aj    = part + (size_t)16 * NFEAT * NFEAT;    // 512*512
  float* U     = Aj + (size_t)NFEAT * NFEAT;           // 512*512 [k][f]
  float* Ut    = U + (size_t)NFEAT * NFEAT;            // 512*512 [f][k]
  float* mnsum = Ut + (size_t)NFEAT * NFEAT;           // 512
  float* mn    = mnsum + NFEAT;
  float* stddv = mn + NFEAT;
  float* istdd = stddv + NFEAT;
  float* utmn  = istdd + NFEAT;
  unsigned int* bar = (unsigned int*)(utmn + NFEAT);
  float* rbuf  = im;                                   // reuse im for rec

  // zero mnsum..utmn (5*NFEAT floats) + bar (16B slack)
  hipMemsetAsync(mnsum, 0, (5 * NFEAT) * sizeof(float) + 64, stream);
  k_gather<<<4096, 256, 0, stream>>>(x, im, mnsum);
  k_mean<<<2, 256, 0, stream>>>(mnsum, mn);
  k_covpart<<<256, 256, 0, stream>>>(im, part);
  k_covfin<<<512, 256, 0, stream>>>(part, mn, Aj);
  k_jacobi_persist<<<16, 512, 0, stream>>>(Aj, bar);
  k_eigfin<<<512, 256, 0, stream>>>(Aj, mn, U, Ut, stddv, istdd, utmn);
  k_proj<<<2048, 256, 0, stream>>>(im, Ut, utmn, stddv, istdd, clampv, bitsp, Y);
  k_rec<<<2048, 256, 0, stream>>>(Y, U, mn, rbuf);
  k_scatter<<<4096, 256, 0, stream>>>(rbuf, (float*)d_out);
}